// Round 9
// baseline (582.388 us; speedup 1.0000x reference)
//
#include <hip/hip_runtime.h>
#include <hip/hip_cooperative_groups.h>

namespace cg = cooperative_groups;

// PointPillars voxelization, MI355X — round 9: single cooperative kernel.
// Grid: 400 x 400 x 1 = 160000 cells. MAX_VOX=60000, MAX_PTS=32, feats=5.
// d_out (float32): voxels [60000,32,5], coords zyx [60000,3], num_points [60000]
//
// Theory: rounds 6/7 showed per-kernel work is cheap (<42us each) but the
// 6-dispatch serial chain + intermediate arrays (excl 640KB, blockSums,
// nvox round-trips) carry ~50us of boundary overhead. Fuse everything into
// one cooperative kernel with grid.sync() between phases; per-thread scan
// prefixes stay in REGISTERS across syncs (excl array eliminated), nvox
// stays in LDS per block.

constexpr int GXc = 400;
constexpr int GYc = 400;
constexpr int NCELL = GXc * GYc;       // 160000
constexpr int MAXV  = 60000;
constexpr int MAXP  = 32;
constexpr int NF    = 5;

constexpr int NBLK = 1024;             // cooperative grid (4 blocks/CU x 256 CUs)
constexpr int BT   = 256;              // threads per block (4 waves)
constexpr int NSCB = (NCELL + BT - 1) / BT;              // 625 scan tiles
constexpr int VITER = (MAXV + NBLK * 4 - 1) / (NBLK * 4); // 15 finalize iters

__device__ __forceinline__ int point_cell(float x, float y, float z) {
    // floor((p - vmin)/vsize), vsize=(0.25,0.25,8), vmin=(-50,-50,-5) — exact
    int cx = (int)floorf((x + 50.0f) * 4.0f);
    int cy = (int)floorf((y + 50.0f) * 4.0f);
    int cz = (int)floorf((z + 5.0f) * 0.125f);
    if (cx < 0 || cx >= GXc || cy < 0 || cy >= GYc || cz != 0) return -1;
    return cy * GXc + cx;
}

__global__ void __launch_bounds__(BT, 4)
k_fused(const float* __restrict__ pts, int N,
        unsigned char* __restrict__ occupied, int* __restrict__ cellId,
        int* __restrict__ blockSums, int* __restrict__ voxId,
        int* __restrict__ cellOfVox, int* __restrict__ vcount,
        int* __restrict__ slots,
        float* __restrict__ outVox, float* __restrict__ outCoord,
        float* __restrict__ outNum) {
    cg::grid_group grid = cg::this_grid();
    const int tid = threadIdx.x;
    const int bid = blockIdx.x;
    const int gtid = bid * BT + tid;
    const int NT = NBLK * BT;

    __shared__ int sA[BT];              // phase-2 tile scan
    __shared__ int sB[768];             // phase-3 blockSums scan (625 padded)
    __shared__ int s_nvox;
    __shared__ float s_dat[4][MAXP * NF];
    __shared__ int   s_key[4][MAXP];
    __shared__ int   s_srt[4][MAXP];

    // ---- Phase 1: bin all points (cellId coalesced, occupancy byte flags) ----
    for (int i = gtid; i < N; i += NT) {
        const float* p = pts + (size_t)i * NF;
        int c = point_cell(p[0], p[1], p[2]);
        cellId[i] = c;
        if (c >= 0) occupied[c] = 1;   // benign same-value race
    }
    grid.sync();

    // ---- Phase 2: per-tile (256-cell) scan; prefix kept in registers ----
    int flag = 0, thrExcl = 0;
    if (bid < NSCB) {                   // uniform branch per block
        int c = bid * BT + tid;         // NSCB*BT == NCELL exactly
        flag = occupied[c] ? 1 : 0;
        sA[tid] = flag;
        __syncthreads();
        for (int off = 1; off < BT; off <<= 1) {
            int t = (tid >= off) ? sA[tid - off] : 0;
            __syncthreads();
            sA[tid] += t;
            __syncthreads();
        }
        thrExcl = sA[tid] - flag;
        if (tid == BT - 1) blockSums[bid] = sA[tid];
    }
    grid.sync();

    // ---- Phase 3: every block scans the 625 block sums in LDS ----
    sB[tid]       = (tid       < NSCB) ? blockSums[tid]       : 0;
    sB[tid + 256] = (tid + 256 < NSCB) ? blockSums[tid + 256] : 0;
    sB[tid + 512] = (tid + 512 < NSCB) ? blockSums[tid + 512] : 0;
    __syncthreads();
    for (int base = 0; base < 768; base += 256) {
        for (int off = 1; off < 256; off <<= 1) {
            int t = (tid >= off) ? sB[base + tid - off] : 0;
            __syncthreads();
            sB[base + tid] += t;
            __syncthreads();
        }
    }
    int c0 = sB[255];
    sB[256 + tid] += c0;
    __syncthreads();
    int c1 = sB[511];
    sB[512 + tid] += c1;
    __syncthreads();
    if (tid == 0) {
        int tot = sB[NSCB - 1];
        s_nvox = tot < MAXV ? tot : MAXV;
    }
    if (bid < NSCB) {
        int base = (bid == 0) ? 0 : sB[bid - 1];   // LDS broadcast
        int v = base + thrExcl;
        int c = bid * BT + tid;
        int vid = (flag && v < MAXV) ? v : -1;
        voxId[c] = vid;
        if (vid >= 0) cellOfVox[vid] = c;
    }
    grid.sync();

    // ---- Phase 4: scatter live points into voxel-indexed slots ----
    for (int i = gtid; i < N; i += NT) {
        int c = cellId[i];
        if (c >= 0) {
            int v = voxId[c];
            if (v >= 0) {
                int pos = atomicAdd(&vcount[v], 1);
                if (pos < MAXP) slots[v * MAXP + pos] = i;
            }
        }
    }
    grid.sync();

    // ---- Phase 5: wave-per-voxel finalize (rank-sort, gather, float4 out) ----
    int nvox = s_nvox;
    int wv = tid >> 6, lane = tid & 63;
    for (int k = 0; k < VITER; k++) {
        int v = k * (NBLK * 4) + bid * 4 + wv;
        bool valid = v < MAXV;
        bool live = valid && (v < nvox);
        int c = 0, num = 0;
        if (live) {
            c = cellOfVox[v];
            int cnt = vcount[v];
            num = cnt < MAXP ? cnt : MAXP;
        }
        if (lane < MAXP)
            s_key[wv][lane] = (live && lane < num) ? slots[v * MAXP + lane]
                                                   : 0x7fffffff;
        #pragma unroll
        for (int q = 0; q < 3; q++) {
            int idx = lane + 64 * q;
            if (idx < MAXP * NF) s_dat[wv][idx] = 0.0f;
        }
        __syncthreads();

        if (lane < MAXP) {
            int key = s_key[wv][lane];
            int rank = 0;
            #pragma unroll
            for (int j = 0; j < MAXP; j++) rank += (s_key[wv][j] < key) ? 1 : 0;
            if (live && lane < num) s_srt[wv][rank] = key;
        }
        __syncthreads();

        if (live && lane < num) {
            int p = s_srt[wv][lane];
            size_t byte0 = (size_t)p * 20;
            float r0, r1, r2, r3, r4, r5, r6, r7;
            int sel;
            if (byte0 + 32 <= (size_t)N * 20) {
                const float4* f4 = (const float4*)pts;
                size_t w = byte0 >> 4;
                sel = (int)((byte0 & 15) >> 2);          // 0..3
                float4 qa = f4[w], qb = f4[w + 1];
                r0 = qa.x; r1 = qa.y; r2 = qa.z; r3 = qa.w;
                r4 = qb.x; r5 = qb.y; r6 = qb.z; r7 = qb.w;
            } else {                                      // last row: no OOB tail
                const float* s = pts + (size_t)p * NF;
                r0 = s[0]; r1 = s[1]; r2 = s[2]; r3 = s[3]; r4 = s[4];
                r5 = r6 = r7 = 0.0f; sel = 0;
            }
            float o0 = sel == 0 ? r0 : sel == 1 ? r1 : sel == 2 ? r2 : r3;
            float o1 = sel == 0 ? r1 : sel == 1 ? r2 : sel == 2 ? r3 : r4;
            float o2 = sel == 0 ? r2 : sel == 1 ? r3 : sel == 2 ? r4 : r5;
            float o3 = sel == 0 ? r3 : sel == 1 ? r4 : sel == 2 ? r5 : r6;
            float o4 = sel == 0 ? r4 : sel == 1 ? r5 : sel == 2 ? r6 : r7;
            float* d = &s_dat[wv][lane * NF];
            d[0] = o0; d[1] = o1; d[2] = o2; d[3] = o3; d[4] = o4;
        }
        __syncthreads();

        if (valid) {
            const float4* sv = (const float4*)s_dat[wv];
            float4* dst = (float4*)(outVox + (size_t)v * (MAXP * NF));
            if (lane < 40) dst[lane] = sv[lane];
            if (lane == 40) outCoord[(size_t)v * 3 + 0] = 0.0f;
            if (lane == 41) outCoord[(size_t)v * 3 + 1] = live ? (float)(c / GXc) : 0.0f;
            if (lane == 42) outCoord[(size_t)v * 3 + 2] = live ? (float)(c % GXc) : 0.0f;
            if (lane == 43) outNum[v] = live ? (float)num : 0.0f;
        }
        __syncthreads();   // protect s_key/s_dat before next iteration
    }
}

extern "C" void kernel_launch(void* const* d_in, const int* in_sizes, int n_in,
                              void* d_out, int out_size, void* d_ws, size_t ws_size,
                              hipStream_t stream) {
    const float* pts = (const float*)d_in[0];
    int N = in_sizes[0] / NF;

    float* out      = (float*)d_out;
    float* outVox   = out;
    float* outCoord = out + (size_t)MAXV * MAXP * NF;
    float* outNum   = outCoord + (size_t)MAXV * 3;

    char* ws = (char*)d_ws;
    auto take = [&](size_t bytes) {
        char* p = ws;
        ws += (bytes + 255) & ~(size_t)255;
        return p;
    };
    // occupied + vcount contiguous -> single 400KB memset.
    unsigned char* occupied = (unsigned char*)take((size_t)NCELL);
    int* vcount    = (int*)take((size_t)MAXV * 4);
    int* cellId    = (int*)take((size_t)N * 4);
    int* blockSums = (int*)take((size_t)768 * 4);
    int* voxId     = (int*)take((size_t)NCELL * 4);
    int* cellOfVox = (int*)take((size_t)MAXV * 4);
    int* slots     = (int*)take((size_t)MAXV * MAXP * 4);    // 7.68 MB

    size_t zeroBytes = (size_t)((char*)(vcount + MAXV) - (char*)occupied);
    hipMemsetAsync(occupied, 0, zeroBytes, stream);

    void* args[] = { (void*)&pts, (void*)&N, (void*)&occupied, (void*)&cellId,
                     (void*)&blockSums, (void*)&voxId, (void*)&cellOfVox,
                     (void*)&vcount, (void*)&slots,
                     (void*)&outVox, (void*)&outCoord, (void*)&outNum };
    hipLaunchCooperativeKernel((void*)k_fused, dim3(NBLK), dim3(BT),
                               args, 0, stream);
}

// Round 10
// 120.748 us; speedup vs baseline: 4.8232x; 4.8232x over previous
//
#include <hip/hip_runtime.h>

// PointPillars voxelization, MI355X — round 10.
// Grid: 400 x 400 x 1 = 160000 cells. MAX_VOX=60000, MAX_PTS=32, feats=5.
// d_out (float32): voxels [60000,32,5], coords zyx [60000,3], num_points [60000]
//
// Round-10: revert cooperative fusion (grid.sync costs ~100us on 8-XCD).
// Keep r6 multi-kernel pipeline; raise memory-level parallelism where the
// latency is: finalize gathers 4 voxels/wave with all 64 lanes issuing 4
// independent float4 loads (was: 32 lanes x 2); scatter2 does 8 pts/thread
// with 8 voxId gathers in flight. No __syncthreads in finalize (wave-lockstep).

constexpr int GXc = 400;
constexpr int GYc = 400;
constexpr int NCELL = GXc * GYc;       // 160000
constexpr int MAXV  = 60000;
constexpr int MAXP  = 32;
constexpr int NF    = 5;

constexpr int SCAN_B = 256;
constexpr int SCAN_E = 8;
constexpr int SCAN_TILE = SCAN_B * SCAN_E;                    // 2048
constexpr int NSCANBLK = (NCELL + SCAN_TILE - 1) / SCAN_TILE; // 79

__device__ __forceinline__ int point_cell(float x, float y, float z) {
    // floor((p - vmin)/vsize), vsize=(0.25,0.25,8), vmin=(-50,-50,-5) — exact
    int cx = (int)floorf((x + 50.0f) * 4.0f);
    int cy = (int)floorf((y + 50.0f) * 4.0f);
    int cz = (int)floorf((z + 5.0f) * 0.125f);
    if (cx < 0 || cx >= GXc || cy < 0 || cy >= GYc || cz != 0) return -1;
    return cy * GXc + cx;
}

// Pass 1: per-point cell id (coalesced int4 store) + occupancy bytes. No atomics.
__global__ void __launch_bounds__(256)
k_bin(const float* __restrict__ pts, int N,
      unsigned char* __restrict__ occupied, int* __restrict__ cellId) {
    int t = blockIdx.x * blockDim.x + threadIdx.x;
    int i0 = t * 4;
    if (i0 >= N) return;
    if (N - i0 >= 4) {
        const float4* src = (const float4*)(pts + (size_t)i0 * NF);
        float4 q0 = src[0], q1 = src[1], q2 = src[2], q3 = src[3], q4 = src[4];
        float f[20];
        *(float4*)(f + 0)  = q0; *(float4*)(f + 4)  = q1; *(float4*)(f + 8)  = q2;
        *(float4*)(f + 12) = q3; *(float4*)(f + 16) = q4;
        int cs[4];
        #pragma unroll
        for (int k = 0; k < 4; k++)
            cs[k] = point_cell(f[k * 5 + 0], f[k * 5 + 1], f[k * 5 + 2]);
        *(int4*)(cellId + i0) = make_int4(cs[0], cs[1], cs[2], cs[3]);
        #pragma unroll
        for (int k = 0; k < 4; k++)
            if (cs[k] >= 0) occupied[cs[k]] = 1;   // benign same-value race
    } else {
        for (int k = 0; k < N - i0; k++) {
            const float* p = pts + (size_t)(i0 + k) * NF;
            int c = point_cell(p[0], p[1], p[2]);
            cellId[i0 + k] = c;
            if (c >= 0) occupied[c] = 1;
        }
    }
}

// Per-2048-cell-tile local exclusive scan of occupancy flags (byte input).
__global__ void k_scanA(const unsigned char* __restrict__ occupied,
                        int* __restrict__ excl, int* __restrict__ blockSums) {
    __shared__ int sh[SCAN_B];
    int base = blockIdx.x * SCAN_TILE;
    int idx0 = base + threadIdx.x * SCAN_E;           // 8-byte aligned
    unsigned long long occ8 = 0;
    if (idx0 < NCELL) occ8 = *(const unsigned long long*)(occupied + idx0);
    int vals[SCAN_E];
    int sum = 0;
    #pragma unroll
    for (int e = 0; e < SCAN_E; e++) {
        int v = (int)((occ8 >> (8 * e)) & 1ull);
        vals[e] = sum;
        sum += v;
    }
    sh[threadIdx.x] = sum;
    __syncthreads();
    for (int off = 1; off < SCAN_B; off <<= 1) {
        int t = (threadIdx.x >= (unsigned)off) ? sh[threadIdx.x - off] : 0;
        __syncthreads();
        sh[threadIdx.x] += t;
        __syncthreads();
    }
    int thrExcl = (threadIdx.x == 0) ? 0 : sh[threadIdx.x - 1];
    #pragma unroll
    for (int e = 0; e < SCAN_E; e++) {
        int idx = idx0 + e;
        if (idx < NCELL) excl[idx] = thrExcl + vals[e];
    }
    if (threadIdx.x == SCAN_B - 1) blockSums[blockIdx.x] = sh[SCAN_B - 1];
}

// Re-scan the 79 block sums in LDS per block; emit per-cell voxel id
// (-1 for empty or >= MAXV), the voxel->cell inverse map, and nvox.
__global__ void k_scanB(const unsigned char* __restrict__ occupied,
                        const int* __restrict__ excl,
                        const int* __restrict__ blockSums,
                        int* __restrict__ voxId,
                        int* __restrict__ cellOfVox,
                        int* __restrict__ nvoxOut) {
    __shared__ int sb[128];
    int tid = threadIdx.x;
    if (tid < 128) sb[tid] = (tid < NSCANBLK) ? blockSums[tid] : 0;
    __syncthreads();
    for (int off = 1; off < 128; off <<= 1) {
        int t = (tid < 128 && tid >= off) ? sb[tid - off] : 0;
        __syncthreads();
        if (tid < 128) sb[tid] += t;
        __syncthreads();
    }
    int c = blockIdx.x * blockDim.x + tid;
    if (c < NCELL) {
        int vi = -1;
        if (occupied[c]) {
            int blk = c / SCAN_TILE;
            int basev = (blk == 0) ? 0 : sb[blk - 1];
            int v = basev + excl[c];
            if (v < MAXV) { vi = v; cellOfVox[v] = c; }
        }
        voxId[c] = vi;
    }
    if (blockIdx.x == 0 && tid == 0) {
        int tot = sb[NSCANBLK - 1];
        *nvoxOut = tot < MAXV ? tot : MAXV;
    }
}

// Pass 2: 8 points/thread, 8 voxId gathers in flight before atomics.
__global__ void __launch_bounds__(256)
k_scatter2(const int* __restrict__ cellId, int N,
           const int* __restrict__ voxId,
           int* __restrict__ vcount, int* __restrict__ slots) {
    int t = blockIdx.x * blockDim.x + threadIdx.x;
    int i0 = t * 8;
    if (i0 >= N) return;
    if (N - i0 >= 8) {
        int4 a = *(const int4*)(cellId + i0);
        int4 b = *(const int4*)(cellId + i0 + 4);
        int cs[8] = {a.x, a.y, a.z, a.w, b.x, b.y, b.z, b.w};
        int vs[8];
        #pragma unroll
        for (int k = 0; k < 8; k++)
            vs[k] = (cs[k] >= 0) ? voxId[cs[k]] : -1;   // independent gathers
        #pragma unroll
        for (int k = 0; k < 8; k++) {
            if (vs[k] >= 0) {
                int pos = atomicAdd(&vcount[vs[k]], 1);
                if (pos < MAXP) slots[vs[k] * MAXP + pos] = i0 + k;
            }
        }
    } else {
        for (int k = 0; k < N - i0; k++) {
            int c = cellId[i0 + k];
            if (c >= 0) {
                int v = voxId[c];
                if (v >= 0) {
                    int pos = atomicAdd(&vcount[v], 1);
                    if (pos < MAXP) slots[v * MAXP + pos] = i0 + k;
                }
            }
        }
    }
}

// Finalize: 4 voxels per WAVE. lane = 32*h + s: handles slot s of voxels
// vb+h and vb+2+h. All 64 lanes gather (4 float4 in flight). Wave-internal
// LDS only -> zero barriers. Output: 4 contiguous voxels, coalesced float4.
__global__ void __launch_bounds__(256)
k_finalize(const float* __restrict__ pts, int N,
           const int* __restrict__ vcount,
           const int* __restrict__ slots,
           const int* __restrict__ cellOfVox,
           const int* __restrict__ nvoxPtr,
           float* __restrict__ outVox,
           float* __restrict__ outCoord,
           float* __restrict__ outNum) {
    __shared__ int   s_key[4][4][MAXP];
    __shared__ int   s_srt[4][4][MAXP];
    __shared__ float s_dat[4][4][MAXP * NF];   // 640 floats per wave

    int tid  = threadIdx.x;
    int wv   = tid >> 6, lane = tid & 63;
    int h    = lane >> 5, s = lane & 31;
    int vb   = (blockIdx.x * 4 + wv) * 4;      // MAXV = 3750*16, exact
    int nvox = *nvoxPtr;

    int u0 = vb + h, u1 = vb + 2 + h;
    bool live0 = u0 < nvox, live1 = u1 < nvox;
    int num0 = 0, num1 = 0;
    if (live0) { int cnt = vcount[u0]; num0 = cnt < MAXP ? cnt : MAXP; }
    if (live1) { int cnt = vcount[u1]; num1 = cnt < MAXP ? cnt : MAXP; }

    // keys for both voxels (independent loads)
    int k0 = (live0 && s < num0) ? slots[u0 * MAXP + s] : 0x7fffffff;
    int k1 = (live1 && s < num1) ? slots[u1 * MAXP + s] : 0x7fffffff;
    s_key[wv][h][s]     = k0;
    s_key[wv][2 + h][s] = k1;

    // zero the wave's 640-float data tile (10 per lane)
    float* flat = (float*)s_dat[wv];
    #pragma unroll
    for (int q = 0; q < 10; q++) flat[q * 64 + lane] = 0.0f;

    // rank-sort both voxels (keys are distinct point indices)
    int rank0 = 0, rank1 = 0;
    #pragma unroll
    for (int j = 0; j < MAXP; j++) rank0 += (s_key[wv][h][j] < k0) ? 1 : 0;
    #pragma unroll
    for (int j = 0; j < MAXP; j++) rank1 += (s_key[wv][2 + h][j] < k1) ? 1 : 0;
    bool g0 = live0 && s < num0, g1 = live1 && s < num1;
    if (g0) s_srt[wv][h][rank0]     = k0;
    if (g1) s_srt[wv][2 + h][rank1] = k1;

    // batched gather: both rows' float4 loads issued before any consumption
    int p0 = g0 ? s_srt[wv][h][s]     : 0;
    int p1 = g1 ? s_srt[wv][2 + h][s] : 0;
    float4 qa0, qb0, qa1, qb1;
    int sel0 = -1, sel1 = -1;
    size_t lim = (size_t)N * 20;
    const float4* f4 = (const float4*)pts;
    if (g0) {
        size_t b = (size_t)p0 * 20;
        if (b + 32 <= lim) {
            sel0 = (int)((b & 15) >> 2);
            size_t w = b >> 4;
            qa0 = f4[w]; qb0 = f4[w + 1];
        }
    }
    if (g1) {
        size_t b = (size_t)p1 * 20;
        if (b + 32 <= lim) {
            sel1 = (int)((b & 15) >> 2);
            size_t w = b >> 4;
            qa1 = f4[w]; qb1 = f4[w + 1];
        }
    }
    if (g0) {
        float r0, r1, r2, r3, r4, r5, r6, r7;
        if (sel0 >= 0) {
            r0 = qa0.x; r1 = qa0.y; r2 = qa0.z; r3 = qa0.w;
            r4 = qb0.x; r5 = qb0.y; r6 = qb0.z; r7 = qb0.w;
        } else {   // last row of pts: scalar tail-safe path
            const float* sp = pts + (size_t)p0 * NF;
            r0 = sp[0]; r1 = sp[1]; r2 = sp[2]; r3 = sp[3]; r4 = sp[4];
            r5 = r6 = r7 = 0.0f; sel0 = 0;
        }
        float o0 = sel0 == 0 ? r0 : sel0 == 1 ? r1 : sel0 == 2 ? r2 : r3;
        float o1 = sel0 == 0 ? r1 : sel0 == 1 ? r2 : sel0 == 2 ? r3 : r4;
        float o2 = sel0 == 0 ? r2 : sel0 == 1 ? r3 : sel0 == 2 ? r4 : r5;
        float o3 = sel0 == 0 ? r3 : sel0 == 1 ? r4 : sel0 == 2 ? r5 : r6;
        float o4 = sel0 == 0 ? r4 : sel0 == 1 ? r5 : sel0 == 2 ? r6 : r7;
        float* d = &s_dat[wv][h][s * NF];
        d[0] = o0; d[1] = o1; d[2] = o2; d[3] = o3; d[4] = o4;
    }
    if (g1) {
        float r0, r1, r2, r3, r4, r5, r6, r7;
        if (sel1 >= 0) {
            r0 = qa1.x; r1 = qa1.y; r2 = qa1.z; r3 = qa1.w;
            r4 = qb1.x; r5 = qb1.y; r6 = qb1.z; r7 = qb1.w;
        } else {
            const float* sp = pts + (size_t)p1 * NF;
            r0 = sp[0]; r1 = sp[1]; r2 = sp[2]; r3 = sp[3]; r4 = sp[4];
            r5 = r6 = r7 = 0.0f; sel1 = 0;
        }
        float o0 = sel1 == 0 ? r0 : sel1 == 1 ? r1 : sel1 == 2 ? r2 : r3;
        float o1 = sel1 == 0 ? r1 : sel1 == 1 ? r2 : sel1 == 2 ? r3 : r4;
        float o2 = sel1 == 0 ? r2 : sel1 == 1 ? r3 : sel1 == 2 ? r4 : r5;
        float o3 = sel1 == 0 ? r3 : sel1 == 1 ? r4 : sel1 == 2 ? r5 : r6;
        float o4 = sel1 == 0 ? r4 : sel1 == 1 ? r5 : sel1 == 2 ? r6 : r7;
        float* d = &s_dat[wv][2 + h][s * NF];
        d[0] = o0; d[1] = o1; d[2] = o2; d[3] = o3; d[4] = o4;
    }

    // coalesced output: 4 voxels x 40 float4 = 160 float4 per wave
    const float4* sv = (const float4*)s_dat[wv];
    float4* dst = (float4*)(outVox + (size_t)vb * (MAXP * NF));
    #pragma unroll
    for (int q = 0; q < 3; q++) {
        int idx = q * 64 + lane;
        if (idx < 160) dst[idx] = sv[idx];
    }
    if (lane < 4) {
        int v = vb + lane;
        bool lv = v < nvox;
        int c = lv ? cellOfVox[v] : 0;
        int cnt = lv ? vcount[v] : 0;
        int num = cnt < MAXP ? cnt : MAXP;
        outNum[v] = lv ? (float)num : 0.0f;
        outCoord[(size_t)v * 3 + 0] = 0.0f;
        outCoord[(size_t)v * 3 + 1] = lv ? (float)(c / GXc) : 0.0f;
        outCoord[(size_t)v * 3 + 2] = lv ? (float)(c % GXc) : 0.0f;
    }
}

extern "C" void kernel_launch(void* const* d_in, const int* in_sizes, int n_in,
                              void* d_out, int out_size, void* d_ws, size_t ws_size,
                              hipStream_t stream) {
    const float* pts = (const float*)d_in[0];
    int N = in_sizes[0] / NF;

    float* out      = (float*)d_out;
    float* outVox   = out;
    float* outCoord = out + (size_t)MAXV * MAXP * NF;
    float* outNum   = outCoord + (size_t)MAXV * 3;

    char* ws = (char*)d_ws;
    auto take = [&](size_t bytes) {
        char* p = ws;
        ws += (bytes + 255) & ~(size_t)255;
        return p;
    };
    // occupied + vcount contiguous -> single 400KB memset.
    unsigned char* occupied = (unsigned char*)take((size_t)NCELL);
    int* vcount    = (int*)take((size_t)MAXV * 4);
    int* cellId    = (int*)take((size_t)((N + 7) & ~7) * 4);
    int* excl      = (int*)take((size_t)NCELL * 4);
    int* blockSums = (int*)take((size_t)128 * 4);
    int* voxId     = (int*)take((size_t)NCELL * 4);
    int* cellOfVox = (int*)take((size_t)MAXV * 4);
    int* slots     = (int*)take((size_t)MAXV * MAXP * 4);    // 7.68 MB
    int* nvoxBuf   = (int*)take(256);

    size_t zeroBytes = (size_t)((char*)(vcount + MAXV) - (char*)occupied);
    hipMemsetAsync(occupied, 0, zeroBytes, stream);

    int nb4 = ((N + 3) / 4 + 255) / 256;
    k_bin<<<nb4, 256, 0, stream>>>(pts, N, occupied, cellId);
    k_scanA<<<NSCANBLK, SCAN_B, 0, stream>>>(occupied, excl, blockSums);
    k_scanB<<<(NCELL + 255) / 256, 256, 0, stream>>>(occupied, excl, blockSums,
                                                     voxId, cellOfVox, nvoxBuf);
    int nb8 = ((N + 7) / 8 + 255) / 256;
    k_scatter2<<<nb8, 256, 0, stream>>>(cellId, N, voxId, vcount, slots);
    k_finalize<<<MAXV / 16, 256, 0, stream>>>(pts, N, vcount, slots, cellOfVox,
                                              nvoxBuf, outVox, outCoord, outNum);
}

// Round 12
// 114.051 us; speedup vs baseline: 5.1064x; 1.0587x over previous
//
#include <hip/hip_runtime.h>

// PointPillars voxelization, MI355X — round 11 (resubmit; prior attempt hit
// GPU-acquisition timeout, kernel never ran).
// Grid: 400 x 400 x 1 = 160000 cells. MAX_VOX=60000, MAX_PTS=32, feats=5.
// d_out (float32): voxels [60000,32,5], coords zyx [60000,3], num_points [60000]
//
// Round-11: forward-flow data movement. The finalize random point-gather
// (300k x 20B rows, full HBM latency each) is eliminated by having the
// scatter pass write full 32B records (x,y,z,f3,f4,idx) into voxel-indexed
// vdata; finalize then reads densely, rank-sorts by embedded idx, and writes
// coalesced output. cellId array dropped (scatter recomputes cells from the
// L3-resident pts). vcount zeroing folded into scanB; memset = 160KB.

constexpr int GXc = 400;
constexpr int GYc = 400;
constexpr int NCELL = GXc * GYc;       // 160000
constexpr int MAXV  = 60000;
constexpr int MAXP  = 32;
constexpr int NF    = 5;

constexpr int SCAN_B = 256;
constexpr int SCAN_E = 8;
constexpr int SCAN_TILE = SCAN_B * SCAN_E;                    // 2048
constexpr int NSCANBLK = (NCELL + SCAN_TILE - 1) / SCAN_TILE; // 79

__device__ __forceinline__ int point_cell(float x, float y, float z) {
    // floor((p - vmin)/vsize), vsize=(0.25,0.25,8), vmin=(-50,-50,-5) — exact
    int cx = (int)floorf((x + 50.0f) * 4.0f);
    int cy = (int)floorf((y + 50.0f) * 4.0f);
    int cz = (int)floorf((z + 5.0f) * 0.125f);
    if (cx < 0 || cx >= GXc || cy < 0 || cy >= GYc || cz != 0) return -1;
    return cy * GXc + cx;
}

// Pass 1: occupancy bytes only (no cellId, no atomics).
__global__ void __launch_bounds__(256)
k_bin(const float* __restrict__ pts, int N, unsigned char* __restrict__ occupied) {
    int t = blockIdx.x * blockDim.x + threadIdx.x;
    int i0 = t * 4;
    if (i0 >= N) return;
    if (N - i0 >= 4) {
        const float4* src = (const float4*)(pts + (size_t)i0 * NF);
        float4 q0 = src[0], q1 = src[1], q2 = src[2], q3 = src[3], q4 = src[4];
        float f[20];
        *(float4*)(f + 0)  = q0; *(float4*)(f + 4)  = q1; *(float4*)(f + 8)  = q2;
        *(float4*)(f + 12) = q3; *(float4*)(f + 16) = q4;
        #pragma unroll
        for (int k = 0; k < 4; k++) {
            int c = point_cell(f[k * 5 + 0], f[k * 5 + 1], f[k * 5 + 2]);
            if (c >= 0) occupied[c] = 1;          // benign same-value race
        }
    } else {
        for (int k = 0; k < N - i0; k++) {
            const float* p = pts + (size_t)(i0 + k) * NF;
            int c = point_cell(p[0], p[1], p[2]);
            if (c >= 0) occupied[c] = 1;
        }
    }
}

// Per-2048-cell-tile local exclusive scan of occupancy flags (byte input).
__global__ void k_scanA(const unsigned char* __restrict__ occupied,
                        int* __restrict__ excl, int* __restrict__ blockSums) {
    __shared__ int sh[SCAN_B];
    int base = blockIdx.x * SCAN_TILE;
    int idx0 = base + threadIdx.x * SCAN_E;           // 8-byte aligned
    unsigned long long occ8 = 0;
    if (idx0 < NCELL) occ8 = *(const unsigned long long*)(occupied + idx0);
    int vals[SCAN_E];
    int sum = 0;
    #pragma unroll
    for (int e = 0; e < SCAN_E; e++) {
        int v = (int)((occ8 >> (8 * e)) & 1ull);
        vals[e] = sum;
        sum += v;
    }
    sh[threadIdx.x] = sum;
    __syncthreads();
    for (int off = 1; off < SCAN_B; off <<= 1) {
        int t = (threadIdx.x >= (unsigned)off) ? sh[threadIdx.x - off] : 0;
        __syncthreads();
        sh[threadIdx.x] += t;
        __syncthreads();
    }
    int thrExcl = (threadIdx.x == 0) ? 0 : sh[threadIdx.x - 1];
    #pragma unroll
    for (int e = 0; e < SCAN_E; e++) {
        int idx = idx0 + e;
        if (idx < NCELL) excl[idx] = thrExcl + vals[e];
    }
    if (threadIdx.x == SCAN_B - 1) blockSums[blockIdx.x] = sh[SCAN_B - 1];
}

// Re-scan the 79 block sums in LDS per block; emit voxId (-1 dead), the
// voxel->cell inverse map, nvox; zero vcount for live voxels.
__global__ void k_scanB(const unsigned char* __restrict__ occupied,
                        const int* __restrict__ excl,
                        const int* __restrict__ blockSums,
                        int* __restrict__ voxId,
                        int* __restrict__ cellOfVox,
                        int* __restrict__ vcount,
                        int* __restrict__ nvoxOut) {
    __shared__ int sb[128];
    int tid = threadIdx.x;
    if (tid < 128) sb[tid] = (tid < NSCANBLK) ? blockSums[tid] : 0;
    __syncthreads();
    for (int off = 1; off < 128; off <<= 1) {
        int t = (tid < 128 && tid >= off) ? sb[tid - off] : 0;
        __syncthreads();
        if (tid < 128) sb[tid] += t;
        __syncthreads();
    }
    int c = blockIdx.x * blockDim.x + tid;
    if (c < NCELL) {
        int vi = -1;
        if (occupied[c]) {
            int blk = c / SCAN_TILE;
            int basev = (blk == 0) ? 0 : sb[blk - 1];
            int v = basev + excl[c];
            if (v < MAXV) {
                vi = v;
                cellOfVox[v] = c;
                vcount[v] = 0;                    // fold vcount zeroing in here
            }
        }
        voxId[c] = vi;
    }
    if (blockIdx.x == 0 && tid == 0) {
        int tot = sb[NSCANBLK - 1];
        *nvoxOut = tot < MAXV ? tot : MAXV;
    }
}

// Pass 2: read pts coalesced (L3-hot), recompute cells, write full 32B
// records (x,y,z,f3,f4,idx,0,0) into voxel-indexed vdata. No slots array.
__global__ void __launch_bounds__(256)
k_scatter3(const float* __restrict__ pts, int N,
           const int* __restrict__ voxId,
           int* __restrict__ vcount, float* __restrict__ vdata) {
    int t = blockIdx.x * blockDim.x + threadIdx.x;
    int i0 = t * 4;
    if (i0 >= N) return;
    if (N - i0 >= 4) {
        const float4* src = (const float4*)(pts + (size_t)i0 * NF);
        float4 q0 = src[0], q1 = src[1], q2 = src[2], q3 = src[3], q4 = src[4];
        float f[20];
        *(float4*)(f + 0)  = q0; *(float4*)(f + 4)  = q1; *(float4*)(f + 8)  = q2;
        *(float4*)(f + 12) = q3; *(float4*)(f + 16) = q4;
        int cs[4];
        #pragma unroll
        for (int k = 0; k < 4; k++)
            cs[k] = point_cell(f[k * 5 + 0], f[k * 5 + 1], f[k * 5 + 2]);
        int vs[4];
        #pragma unroll
        for (int k = 0; k < 4; k++)
            vs[k] = (cs[k] >= 0) ? voxId[cs[k]] : -1;    // gathers in flight
        #pragma unroll
        for (int k = 0; k < 4; k++) {
            if (vs[k] >= 0) {
                int pos = atomicAdd(&vcount[vs[k]], 1);
                if (pos < MAXP) {
                    float* r = vdata + ((size_t)vs[k] * MAXP + pos) * 8;
                    *(float4*)r = make_float4(f[k*5+0], f[k*5+1], f[k*5+2], f[k*5+3]);
                    *(float4*)(r + 4) = make_float4(f[k*5+4],
                                                    __int_as_float(i0 + k), 0.0f, 0.0f);
                }
            }
        }
    } else {
        for (int k = 0; k < N - i0; k++) {
            const float* p = pts + (size_t)(i0 + k) * NF;
            int c = point_cell(p[0], p[1], p[2]);
            if (c >= 0) {
                int v = voxId[c];
                if (v >= 0) {
                    int pos = atomicAdd(&vcount[v], 1);
                    if (pos < MAXP) {
                        float* r = vdata + ((size_t)v * MAXP + pos) * 8;
                        *(float4*)r = make_float4(p[0], p[1], p[2], p[3]);
                        *(float4*)(r + 4) = make_float4(p[4],
                                                        __int_as_float(i0 + k), 0.0f, 0.0f);
                    }
                }
            }
        }
    }
}

// Finalize: 4 voxels per WAVE, pure throughput. lane = 32*h+s handles slot s
// of voxels vb+h and vb+2+h. Records read densely from vdata, rank-sorted by
// embedded idx, scattered to rank position in LDS from registers, written as
// coalesced float4s. No random reads, no barriers.
__global__ void __launch_bounds__(256)
k_finalize2(const int* __restrict__ vcount,
            const float* __restrict__ vdata,
            const int* __restrict__ cellOfVox,
            const int* __restrict__ nvoxPtr,
            float* __restrict__ outVox,
            float* __restrict__ outCoord,
            float* __restrict__ outNum) {
    __shared__ int   s_key[4][4][MAXP];
    __shared__ float s_dat[4][4][MAXP * NF];   // 640 floats per wave

    int tid  = threadIdx.x;
    int wv   = tid >> 6, lane = tid & 63;
    int h    = lane >> 5, s = lane & 31;
    int vb   = (blockIdx.x * 4 + wv) * 4;      // MAXV = 3750*16, exact
    int nvox = *nvoxPtr;

    int u0 = vb + h, u1 = vb + 2 + h;
    bool live0 = u0 < nvox, live1 = u1 < nvox;
    int num0 = 0, num1 = 0;
    if (live0) { int cnt = vcount[u0]; num0 = cnt < MAXP ? cnt : MAXP; }
    if (live1) { int cnt = vcount[u1]; num1 = cnt < MAXP ? cnt : MAXP; }
    bool g0 = live0 && s < num0, g1 = live1 && s < num1;

    // dense record loads (2 float4 each, both voxels issued together)
    float4 a0, b0, a1, b1;
    if (g0) {
        const float4* r = (const float4*)(vdata + ((size_t)u0 * MAXP + s) * 8);
        a0 = r[0]; b0 = r[1];
    }
    if (g1) {
        const float4* r = (const float4*)(vdata + ((size_t)u1 * MAXP + s) * 8);
        a1 = r[0]; b1 = r[1];
    }
    int k0 = g0 ? __float_as_int(b0.y) : 0x7fffffff;
    int k1 = g1 ? __float_as_int(b1.y) : 0x7fffffff;
    s_key[wv][h][s]     = k0;
    s_key[wv][2 + h][s] = k1;

    // zero the wave's 640-float data tile (10 per lane)
    float* flat = (float*)s_dat[wv];
    #pragma unroll
    for (int q = 0; q < 10; q++) flat[q * 64 + lane] = 0.0f;

    // rank by embedded original index (distinct), then scatter from registers
    int rank0 = 0, rank1 = 0;
    #pragma unroll
    for (int j = 0; j < MAXP; j++) rank0 += (s_key[wv][h][j] < k0) ? 1 : 0;
    #pragma unroll
    for (int j = 0; j < MAXP; j++) rank1 += (s_key[wv][2 + h][j] < k1) ? 1 : 0;
    if (g0) {
        float* d = &s_dat[wv][h][rank0 * NF];
        d[0] = a0.x; d[1] = a0.y; d[2] = a0.z; d[3] = a0.w; d[4] = b0.x;
    }
    if (g1) {
        float* d = &s_dat[wv][2 + h][rank1 * NF];
        d[0] = a1.x; d[1] = a1.y; d[2] = a1.z; d[3] = a1.w; d[4] = b1.x;
    }

    // coalesced output: 4 voxels x 40 float4 = 160 float4 per wave
    const float4* sv = (const float4*)s_dat[wv];
    float4* dst = (float4*)(outVox + (size_t)vb * (MAXP * NF));
    #pragma unroll
    for (int q = 0; q < 3; q++) {
        int idx = q * 64 + lane;
        if (idx < 160) dst[idx] = sv[idx];
    }
    if (lane < 4) {
        int v = vb + lane;
        bool lv = v < nvox;
        int c = lv ? cellOfVox[v] : 0;
        int cnt = lv ? vcount[v] : 0;
        int num = cnt < MAXP ? cnt : MAXP;
        outNum[v] = lv ? (float)num : 0.0f;
        outCoord[(size_t)v * 3 + 0] = 0.0f;
        outCoord[(size_t)v * 3 + 1] = lv ? (float)(c / GXc) : 0.0f;
        outCoord[(size_t)v * 3 + 2] = lv ? (float)(c % GXc) : 0.0f;
    }
}

extern "C" void kernel_launch(void* const* d_in, const int* in_sizes, int n_in,
                              void* d_out, int out_size, void* d_ws, size_t ws_size,
                              hipStream_t stream) {
    const float* pts = (const float*)d_in[0];
    int N = in_sizes[0] / NF;

    float* out      = (float*)d_out;
    float* outVox   = out;
    float* outCoord = out + (size_t)MAXV * MAXP * NF;
    float* outNum   = outCoord + (size_t)MAXV * 3;

    char* ws = (char*)d_ws;
    auto take = [&](size_t bytes) {
        char* p = ws;
        ws += (bytes + 255) & ~(size_t)255;
        return p;
    };
    unsigned char* occupied = (unsigned char*)take((size_t)NCELL);  // 160KB
    int* vcount    = (int*)take((size_t)MAXV * 4);
    int* excl      = (int*)take((size_t)NCELL * 4);
    int* blockSums = (int*)take((size_t)128 * 4);
    int* voxId     = (int*)take((size_t)NCELL * 4);
    int* cellOfVox = (int*)take((size_t)MAXV * 4);
    float* vdata   = (float*)take((size_t)MAXV * MAXP * 8 * 4);     // 61.4MB
    int* nvoxBuf   = (int*)take(256);

    hipMemsetAsync(occupied, 0, (size_t)NCELL, stream);   // only the flags

    int nb4 = ((N + 3) / 4 + 255) / 256;
    k_bin<<<nb4, 256, 0, stream>>>(pts, N, occupied);
    k_scanA<<<NSCANBLK, SCAN_B, 0, stream>>>(occupied, excl, blockSums);
    k_scanB<<<(NCELL + 255) / 256, 256, 0, stream>>>(occupied, excl, blockSums,
                                                     voxId, cellOfVox, vcount, nvoxBuf);
    k_scatter3<<<nb4, 256, 0, stream>>>(pts, N, voxId, vcount, vdata);
    k_finalize2<<<MAXV / 16, 256, 0, stream>>>(vcount, vdata, cellOfVox,
                                               nvoxBuf, outVox, outCoord, outNum);
}